// Round 15
// baseline (651.279 us; speedup 1.0000x reference)
//
#include <hip/hip_runtime.h>
#include <hip/hip_bf16.h>
#include <stdint.h>
#include <stddef.h>

#define NN 25000     // nodes
#define NPAD 25024   // 782*32 (fused8 32-node blocks; also covers gru's 1563*16)
#define NBLK 1563    // gru node blocks of 16
#define NBLK32 782   // fused8 node blocks of 32
#define NE 100000    // edges
#define FEAT 16
#define DD 64
#define NGG 512
#define NJ 1024
#define NS 2048
#define NO 105
#define SLOPE 0.01f
#define NQ 4         // o-quarters
#define TPQ 65       // tiles per quarter: 64 W-tiles + 1 bias tile
#define W2T_ELEMS (NQ*TPQ*1024)   // 266240 bf16
#define NSTRIDE 2080 // bytes per node in LDS
#define LDSB (32*NSTRIDE)         // 66560 -> 2 blocks/CU, 32 waves/CU
#define WG_TILES 28
#define WG_ELEMS (WG_TILES*1024)
#define TOTBLK (NBLK32*NQ)        // 3128 = 8*391 (exact XCD split)

typedef short bf8 __attribute__((ext_vector_type(8)));   // 8 bf16 raw bits (4 VGPR)
typedef float f32x4 __attribute__((ext_vector_type(4)));

__device__ __forceinline__ float lk(float v){ return v > 0.f ? v : SLOPE*v; }
__device__ __forceinline__ unsigned short f2bf(float f){
  __hip_bfloat16 b = __float2bfloat16(f);
  union { __hip_bfloat16 b; unsigned short u; } c; c.b = b; return c.u;
}
__device__ __forceinline__ float bf2f(unsigned short u){ return __uint_as_float(((unsigned int)u)<<16); }
__device__ __forceinline__ float sg(float x){ return 1.f/(1.f+expf(-x)); }
__device__ __forceinline__ unsigned fenc(float f){ unsigned u = __float_as_uint(f); return (u & 0x80000000u) ? ~u : (u | 0x80000000u); }
__device__ __forceinline__ float fdec(unsigned k){ unsigned u = (k & 0x80000000u) ? (k ^ 0x80000000u) : ~k; return __uint_as_float(u); }

// ---------- merged setup kernel: blockIdx ranges select role ----------
#define SB1 6256     // lin0: 25024 node-waves / 4 per block
#define SB2 7296     // + 1040 w2t blocks
#define SB3 7408     // + 112 wgru blocks
#define SB4 7424
#define SB5 7440
#define SB6 7467
__global__ __launch_bounds__(256) void k_setup(const float* __restrict__ x, const float* __restrict__ l0w,
      const float* __restrict__ l0b, float* __restrict__ h, unsigned short* __restrict__ hbf,
      const float* __restrict__ w2, const float* __restrict__ b2, unsigned short* __restrict__ w2t,
      const float* __restrict__ cr, const float* __restrict__ wih, const float* __restrict__ whh,
      unsigned short* __restrict__ wgru,
      const float* __restrict__ jw1, float* __restrict__ w1jT,
      const float* __restrict__ sw1, float* __restrict__ w1sT,
      const float* __restrict__ sw2, float* __restrict__ w2sT){
  int bid = blockIdx.x, tid = threadIdx.x;
  if (bid < SB1){
    int wid = (bid*256 + tid) >> 6;
    int lane = tid & 63;
    if (wid >= NPAD) return;
    if (wid >= NN){ hbf[(size_t)wid*DD + lane] = 0; return; }
    float xv = lane < FEAT ? x[wid*FEAT + lane] : 0.f;
    float acc = l0b[lane];
    #pragma unroll
    for (int f=0; f<FEAT; ++f) acc += __shfl(xv, f) * l0w[lane*FEAT + f];
    float v = lk(acc);
    h[wid*DD + lane] = v;
    hbf[(size_t)wid*DD + lane] = f2bf(v);
  } else if (bid < SB2){
    int u = (bid-SB1)*256 + tid;
    if (u >= W2T_ELEMS) return;
    int j = u & 7;
    int lane = (u >> 3) & 63;
    int kc = (u >> 9) & 1;
    int tg = u >> 10;
    int oq = tg / TPQ, tq = tg - oq*TPQ;
    int r16 = lane & 15, kg = lane >> 4;
    int i = kc*32 + kg*8 + j;
    float v;
    if (tq < 64) v = w2[(size_t)i*4096 + (oq*1024 + tq*16 + r16)];
    else         v = b2[i*64 + oq*16 + r16];
    w2t[u] = f2bf(v);
  } else if (bid < SB3){
    int u = (bid-SB2)*256 + tid;
    if (u >= WG_ELEMS) return;
    int j = u & 7;
    int lane = (u >> 3) & 63;
    int kc = (u >> 9) & 1;
    int t = u >> 10;
    int r16 = lane & 15, kg = lane >> 4;
    int i = kc*32 + kg*8 + j;
    float v;
    if (t < 4)       v = cr[(size_t)i*DD + t*16 + r16];
    else if (t < 16) v = wih[(size_t)((t-4)*16 + r16)*DD + i];
    else             v = whh[(size_t)((t-16)*16 + r16)*DD + i];
    wgru[u] = f2bf(v);
  } else if (bid < SB4){
    int i = (bid-SB3)*256 + tid;
    if (i < DD*DD){ int r = i >> 6, c = i & 63; w1jT[c*DD + r] = jw1[i]; }
  } else if (bid < SB5){
    int i = (bid-SB4)*256 + tid;
    if (i < DD*DD){ int r = i >> 6, c = i & 63; w1sT[c*DD + r] = sw1[i]; }
  } else {
    int i = (bid-SB5)*256 + tid;
    if (i < NO*DD){ int r = i / DD, c = i - r*DD; w2sT[c*NO + r] = sw2[i]; }
  }
}

// ---------- merged histograms ----------
__global__ __launch_bounds__(256) void k_hist2(const int* __restrict__ src, const int* __restrict__ dst,
                                               int* __restrict__ degS, int* __restrict__ degD,
                                               const int* __restrict__ batch, int* __restrict__ ghist){
  int bid = blockIdx.x;
  if (bid < 391){
    int e = bid*256 + threadIdx.x;
    if (e < NE){ atomicAdd(&degS[src[e]], 1); atomicAdd(&degD[dst[e]], 1); }
  } else {
    int n = (bid-391)*256 + threadIdx.x;
    if (n < NN) atomicAdd(&ghist[batch[n]], 1);
  }
}

// ---------- merged scans (rowptr/rowptrD filled to NPAD=25024) ----------
__global__ __launch_bounds__(1024) void k_scan2(const int* __restrict__ degS, const int* __restrict__ degD,
        int* __restrict__ rowptr, int* __restrict__ rowptrD, float* __restrict__ invd,
        const int* __restrict__ ghist, int* __restrict__ gptr){
  __shared__ int wsA[16], wsB[16];
  __shared__ int baseA, baseB;
  int tid = threadIdx.x, lane = tid & 63, wv = tid >> 6;
  if (tid == 0){ baseA = 0; baseB = 0; rowptr[0] = 0; rowptrD[0] = 0; }
  __syncthreads();
  for (int c0 = 0; c0 < NPAD; c0 += 1024){
    int i = c0 + tid;
    int vA = (i < NPAD) ? degS[i] : 0;
    int vB = (i < NPAD) ? degD[i] : 0;
    if (i < NN) invd[i] = vB > 0 ? 1.f/(float)vB : 0.f;
    int sA = vA, sB = vB;
    #pragma unroll
    for (int off=1; off<64; off<<=1){
      int tA = __shfl_up(sA, off), tB = __shfl_up(sB, off);
      if (lane >= off){ sA += tA; sB += tB; }
    }
    if (lane == 63){ wsA[wv] = sA; wsB[wv] = sB; }
    __syncthreads();
    if (wv == 0 && lane < 16){
      int w = wsA[lane];
      #pragma unroll
      for (int off=1; off<16; off<<=1){ int t = __shfl_up(w, off); if (lane >= off) w += t; }
      wsA[lane] = w;
    }
    if (wv == 1 && lane < 16){
      int w = wsB[lane];
      #pragma unroll
      for (int off=1; off<16; off<<=1){ int t = __shfl_up(w, off); if (lane >= off) w += t; }
      wsB[lane] = w;
    }
    __syncthreads();
    int wbA = wv ? wsA[wv-1] : 0;
    int wbB = wv ? wsB[wv-1] : 0;
    if (i < NPAD){ rowptr[i+1] = baseA + wbA + sA; rowptrD[i+1] = baseB + wbB + sB; }
    __syncthreads();
    if (tid == 0){ baseA += wsA[15]; baseB += wsB[15]; }
    __syncthreads();
  }
  int s = (tid < 512) ? ghist[tid] : 0;
  #pragma unroll
  for (int off=1; off<64; off<<=1){ int t = __shfl_up(s, off); if (lane >= off) s += t; }
  if (tid < 512 && lane == 63) wsA[wv] = s;
  __syncthreads();
  if (wv == 0 && lane < 8){
    int w = wsA[lane];
    #pragma unroll
    for (int off=1; off<8; off<<=1){ int t = __shfl_up(w, off); if (lane >= off) w += t; }
    wsA[lane] = w;
  }
  __syncthreads();
  if (tid < 512){
    int wb = wv ? wsA[wv-1] : 0;
    gptr[tid+1] = wb + s;
    if (tid == 0) gptr[0] = 0;
  }
}

// scatter: src-sorted pos gets edge id + dst-sorted position
__global__ __launch_bounds__(256) void k_scatter(const int* __restrict__ src, const int* __restrict__ dst,
                         const int* __restrict__ rowptr, int* __restrict__ cnt,
                         const int* __restrict__ rowptrD, int* __restrict__ cntD,
                         int* __restrict__ sEid, int* __restrict__ sDpos){
  int e = blockIdx.x*blockDim.x + threadIdx.x;
  if (e >= NE) return;
  int s = src[e], d = dst[e];
  int pos = rowptr[s] + atomicAdd(&cnt[s], 1);
  sEid[pos] = e;
  sDpos[pos] = rowptrD[d] + atomicAdd(&cntD[d], 1);
}

// e1 sorted, wave-per-position; pad rows zeroed; ea row read is a wave-broadcast
__global__ __launch_bounds__(256) void k_e1s(const float* __restrict__ ea, const float* __restrict__ w,
                     const float* __restrict__ b, const int* __restrict__ sEid,
                     unsigned short* __restrict__ e1s){
  int pos = (blockIdx.x*blockDim.x + threadIdx.x) >> 6;
  int lane = threadIdx.x & 63;
  if (pos >= NE + 16) return;
  if (pos >= NE){ e1s[(size_t)pos*DD + lane] = 0; return; }
  int e = sEid[pos];
  const float* er = ea + (size_t)e*4;
  float a0 = er[0], a1 = er[1], a2 = er[2], a3 = er[3];
  const float* wr = w + lane*4;
  float acc = b[lane] + a0*wr[0] + a1*wr[1] + a2*wr[2] + a3*wr[3];
  e1s[(size_t)pos*DD + lane] = f2bf(lk(acc));
}

// ---------- fused message kernel: 32-node blocks, 16 waves ----------
// L2 w2t traffic halves vs 16-node blocks (130KB read amortized over 32 nodes).
// 2 blocks/CU x 16 waves = 32 waves/CU. Phase B body = round-11 proven form.
__global__ __launch_bounds__(1024) void k_fused8(const unsigned short* __restrict__ w2t,
                                                const unsigned short* __restrict__ hbf,
                                                const unsigned short* __restrict__ e1s,
                                                const int* __restrict__ sDpos,
                                                const int* __restrict__ rowptr,
                                                float* __restrict__ msgbuf){
  extern __shared__ char smem[];
  int lane = threadIdx.x & 63;
  int wv   = threadIdx.x >> 6;           // 0..15
  // XCD-bijective decode (3128 = 8*391 exact)
  int xcd = blockIdx.x & 7, q = blockIdx.x >> 3;
  int g = xcd*391 + q;
  int n0 = (g >> 2) * 32;
  int oq = g & 3;
  int r16 = lane & 15, kg = lane >> 4;

  // persistent B-fragments for both 16-node groups
  const unsigned short* hp0 = hbf + (size_t)(n0 + r16)*DD;
  const unsigned short* hp1 = hbf + (size_t)(n0 + 16 + r16)*DD;
  bf8 bh00 = *(const bf8*)(hp0 + kg*8);
  bf8 bh01 = *(const bf8*)(hp0 + 32 + kg*8);
  bf8 bh10 = *(const bf8*)(hp1 + kg*8);
  bf8 bh11 = *(const bf8*)(hp1 + 32 + kg*8);

  // phase A: 65 tiles round-robin over 16 waves; 4 MFMA/tile (2 k-chunks x 2 node groups)
  {
    const unsigned short* wq = w2t + (size_t)oq*TPQ*1024;
    int nsw = r16 & 7;
    for (int tq = wv; tq < TPQ; tq += 16){
      const unsigned short* wp = wq + (size_t)tq*1024;
      bf8 a0 = *(const bf8*)(wp + lane*8);
      bf8 a1 = *(const bf8*)(wp + 512 + lane*8);
      f32x4 acc0 = {0.f,0.f,0.f,0.f}, acc1 = {0.f,0.f,0.f,0.f};
      acc0 = __builtin_amdgcn_mfma_f32_16x16x32_bf16(a0, bh00, acc0, 0,0,0);
      acc0 = __builtin_amdgcn_mfma_f32_16x16x32_bf16(a1, bh01, acc0, 0,0,0);
      acc1 = __builtin_amdgcn_mfma_f32_16x16x32_bf16(a0, bh10, acc1, 0,0,0);
      acc1 = __builtin_amdgcn_mfma_f32_16x16x32_bf16(a1, bh11, acc1, 0,0,0);
      unsigned u00 = (unsigned)f2bf(acc0[0]) | ((unsigned)f2bf(acc0[1]) << 16);
      unsigned u01 = (unsigned)f2bf(acc0[2]) | ((unsigned)f2bf(acc0[3]) << 16);
      unsigned long long ull0 = (unsigned long long)u00 | ((unsigned long long)u01 << 32);
      unsigned u10 = (unsigned)f2bf(acc1[0]) | ((unsigned)f2bf(acc1[1]) << 16);
      unsigned u11 = (unsigned)f2bf(acc1[2]) | ((unsigned)f2bf(acc1[3]) << 16);
      unsigned long long ull1 = (unsigned long long)u10 | ((unsigned long long)u11 << 32);
      if (tq < 64){
        int o_rel = tq >> 2;
        int s = ((tq & 3) << 1) + (kg >> 1);
        int slot = s ^ (o_rel & 7) ^ nsw;        // (r16+16)&7 == r16&7, same slot both groups
        size_t base = (size_t)r16*NSTRIDE + o_rel*128 + (slot<<4) + ((kg & 1)*8);
        *(unsigned long long*)(smem + base) = ull0;
        *(unsigned long long*)(smem + base + (size_t)16*NSTRIDE) = ull1;
      } else {
        size_t base = (size_t)r16*NSTRIDE + 2048 + kg*8;
        *(unsigned long long*)(smem + base) = ull0;
        *(unsigned long long*)(smem + base + (size_t)16*NSTRIDE) = ull1;
      }
    }
  }
  __syncthreads();

  // phase B (round-11 proven form): wave wv handles nodes wv and wv+16
  #pragma unroll
  for (int s2 = 0; s2 < 2; ++s2){
    int nl = wv + 16*s2;
    int node = n0 + nl;
    int estart = rowptr[node], eend = rowptr[node + 1];
    const char* ab = smem + (size_t)nl*NSTRIDE;
    int nsw = nl & 7;
    int slot0 = (kg) ^ (r16 & 7) ^ nsw;
    int slot1 = (4 + kg) ^ (r16 & 7) ^ nsw;
    bf8 B0 = *(const bf8*)(ab + r16*128 + (slot0<<4));
    bf8 B1 = *(const bf8*)(ab + r16*128 + (slot1<<4));
    float bias = bf2f(*(const unsigned short*)(ab + 2048 + r16*2));
    for (int eg = estart; eg < eend; eg += 16){
      bf8 af0 = {0,0,0,0,0,0,0,0}, af1 = {0,0,0,0,0,0,0,0};
      int er = eg + r16;
      if (er < eend){
        af0 = *(const bf8*)(e1s + (size_t)er*DD + kg*8);
        af1 = *(const bf8*)(e1s + (size_t)er*DD + 32 + kg*8);
      }
      int ebase = eg + kg*4;
      int dp[4];
      #pragma unroll
      for (int j=0; j<4; ++j){
        int e = ebase + j;
        dp[j] = (e < eend) ? sDpos[e] : -1;
      }
      f32x4 acc = {0.f,0.f,0.f,0.f};
      acc = __builtin_amdgcn_mfma_f32_16x16x32_bf16(af0, B0, acc, 0,0,0);
      acc = __builtin_amdgcn_mfma_f32_16x16x32_bf16(af1, B1, acc, 0,0,0);
      #pragma unroll
      for (int j=0; j<4; ++j){
        if (dp[j] >= 0)
          msgbuf[(size_t)dp[j]*DD + oq*16 + r16] = acc[j] + bias;
      }
    }
  }
}

// ---------- MFMA GRU: block = 16 nodes, 4 waves ----------
__global__ __launch_bounds__(256) void k_gru(float* __restrict__ h, unsigned short* __restrict__ hbf,
                      const float* __restrict__ msgbuf, const int* __restrict__ rowptrD,
                      const float* __restrict__ invd,
                      const unsigned short* __restrict__ wgru,
                      const float* __restrict__ cb,
                      const float* __restrict__ bih, const float* __restrict__ bhh){
  __shared__ float msum[16*68];
  __shared__ unsigned short mbf[16*64];
  __shared__ float iv[16];
  int tid = threadIdx.x;
  int lane = tid & 63, wv = tid >> 6;
  int n0 = blockIdx.x * 16;
  int r16 = lane & 15, kg = lane >> 4;

  const unsigned short* hp = hbf + (size_t)(n0 + r16)*DD;
  bf8 af0 = *(const bf8*)(hp + kg*8);
  bf8 af1 = *(const bf8*)(hp + 32 + kg*8);

  if (tid < 16) iv[tid] = (n0 + tid < NN) ? invd[n0 + tid] : 0.f;
  #pragma unroll
  for (int q=0; q<4; ++q){
    int nl = wv*4 + q;
    int node = n0 + nl;
    float ms = 0.f;
    if (node < NN){
      int pa = rowptrD[node], pb = rowptrD[node+1];
      for (int p=pa; p<pb; ++p) ms += msgbuf[(size_t)p*DD + lane];
    }
    msum[nl*68 + lane] = ms;
  }
  __syncthreads();

  int o = wv*16 + r16;
  {
    const unsigned short* tp = wgru + (size_t)wv*1024;
    bf8 bc0 = *(const bf8*)(tp + lane*8);
    bf8 bc1 = *(const bf8*)(tp + 512 + lane*8);
    f32x4 cacc = {0.f,0.f,0.f,0.f};
    cacc = __builtin_amdgcn_mfma_f32_16x16x32_bf16(af0, bc0, cacc, 0,0,0);
    cacc = __builtin_amdgcn_mfma_f32_16x16x32_bf16(af1, bc1, cacc, 0,0,0);
    float cbo = cb[o];
    int gi_gran = o >> 3;
    #pragma unroll
    for (int j=0; j<4; ++j){
      int nl = kg*4 + j;
      float mval = lk(msum[nl*68 + o]*iv[nl] + cacc[j] + cbo);
      int swz = gi_gran ^ (nl & 7);
      *(unsigned short*)((char*)mbf + nl*128 + (swz<<4) + (o&7)*2) = f2bf(mval);
    }
  }
  __syncthreads();

  bf8 am0 = *(const bf8*)((char*)mbf + r16*128 + (((kg) ^ (r16 & 7))<<4));
  bf8 am1 = *(const bf8*)((char*)mbf + r16*128 + (((4 + kg) ^ (r16 & 7))<<4));

  f32x4 gi_r={0,0,0,0}, gi_z={0,0,0,0}, gi_n={0,0,0,0};
  f32x4 gh_r={0,0,0,0}, gh_z={0,0,0,0}, gh_n={0,0,0,0};
  {
    const unsigned short* t0 = wgru + (size_t)(4 + 0*4 + wv)*1024;
    const unsigned short* t1 = wgru + (size_t)(4 + 1*4 + wv)*1024;
    const unsigned short* t2 = wgru + (size_t)(4 + 2*4 + wv)*1024;
    const unsigned short* u0 = wgru + (size_t)(16 + 0*4 + wv)*1024;
    const unsigned short* u1 = wgru + (size_t)(16 + 1*4 + wv)*1024;
    const unsigned short* u2 = wgru + (size_t)(16 + 2*4 + wv)*1024;
    gi_r = __builtin_amdgcn_mfma_f32_16x16x32_bf16(am0, *(const bf8*)(t0 + lane*8), gi_r, 0,0,0);
    gi_r = __builtin_amdgcn_mfma_f32_16x16x32_bf16(am1, *(const bf8*)(t0 + 512 + lane*8), gi_r, 0,0,0);
    gi_z = __builtin_amdgcn_mfma_f32_16x16x32_bf16(am0, *(const bf8*)(t1 + lane*8), gi_z, 0,0,0);
    gi_z = __builtin_amdgcn_mfma_f32_16x16x32_bf16(am1, *(const bf8*)(t1 + 512 + lane*8), gi_z, 0,0,0);
    gi_n = __builtin_amdgcn_mfma_f32_16x16x32_bf16(am0, *(const bf8*)(t2 + lane*8), gi_n, 0,0,0);
    gi_n = __builtin_amdgcn_mfma_f32_16x16x32_bf16(am1, *(const bf8*)(t2 + 512 + lane*8), gi_n, 0,0,0);
    gh_r = __builtin_amdgcn_mfma_f32_16x16x32_bf16(af0, *(const bf8*)(u0 + lane*8), gh_r, 0,0,0);
    gh_r = __builtin_amdgcn_mfma_f32_16x16x32_bf16(af1, *(const bf8*)(u0 + 512 + lane*8), gh_r, 0,0,0);
    gh_z = __builtin_amdgcn_mfma_f32_16x16x32_bf16(af0, *(const bf8*)(u1 + lane*8), gh_z, 0,0,0);
    gh_z = __builtin_amdgcn_mfma_f32_16x16x32_bf16(af1, *(const bf8*)(u1 + 512 + lane*8), gh_z, 0,0,0);
    gh_n = __builtin_amdgcn_mfma_f32_16x16x32_bf16(af0, *(const bf8*)(u2 + lane*8), gh_n, 0,0,0);
    gh_n = __builtin_amdgcn_mfma_f32_16x16x32_bf16(af1, *(const bf8*)(u2 + 512 + lane*8), gh_n, 0,0,0);
  }
  float bi0 = bih[o], bi1 = bih[64+o], bi2 = bih[128+o];
  float bh0 = bhh[o], bh1 = bhh[64+o], bh2 = bhh[128+o];
  #pragma unroll
  for (int j=0; j<4; ++j){
    int node = n0 + kg*4 + j;
    if (node < NN){
      size_t idx = (size_t)node*DD + o;
      float hv = h[idx];
      float r = sg(gi_r[j] + bi0 + gh_r[j] + bh0);
      float z = sg(gi_z[j] + bi1 + gh_z[j] + bh1);
      float nn = tanhf(gi_n[j] + bi2 + r*(gh_n[j] + bh2));
      float nh = (1.f - z)*nn + z*hv;
      h[idx] = nh;
      hbf[idx] = f2bf(nh);
    }
  }
}

// ---------- heads ----------
__global__ __launch_bounds__(256) void k_jbond(const float* __restrict__ h, const int* __restrict__ idx,
                        const float* __restrict__ w1T, const float* __restrict__ b1,
                        const float* __restrict__ w2, const float* __restrict__ b2,
                        float* __restrict__ jtmp){
  int wid = (blockIdx.x*blockDim.x + threadIdx.x) >> 6;
  int lane = threadIdx.x & 63;
  if (wid >= NJ*2) return;
  int a = idx[wid];
  float f = h[(size_t)a*DD + lane];
  float acc = b1[lane];
  for (int i=0; i<DD; ++i) acc += __shfl(f, i) * w1T[i*DD + lane];
  float p = lk(acc) * w2[lane];
  #pragma unroll
  for (int off=32; off; off>>=1) p += __shfl_xor(p, off);
  if (lane == 0) jtmp[wid] = p + b2[0];
}
__global__ __launch_bounds__(256) void k_jmean(const float* __restrict__ jtmp, float* __restrict__ o){
  int j = blockIdx.x*blockDim.x + threadIdx.x;
  if (j < NJ) o[j] = 0.5f*(jtmp[2*j] + jtmp[2*j+1]);
}
__global__ __launch_bounds__(256) void k_stem1(const float* __restrict__ h, const int* __restrict__ idx,
                        const float* __restrict__ w1T, const float* __restrict__ b1,
                        float* __restrict__ st1){
  int wid = (blockIdx.x*blockDim.x + threadIdx.x) >> 6;
  int lane = threadIdx.x & 63;
  if (wid >= NS) return;
  int a = idx[wid];
  float f = h[(size_t)a*DD + lane];
  float acc = b1[lane];
  for (int i=0; i<DD; ++i) acc += __shfl(f, i) * w1T[i*DD + lane];
  st1[(size_t)wid*DD + lane] = lk(acc);
}
__global__ __launch_bounds__(256) void k_stem2(const float* __restrict__ st1, const float* __restrict__ w2T,
                        const float* __restrict__ b2, float* __restrict__ o){
  int i = blockIdx.x*blockDim.x + threadIdx.x;
  if (i >= NS*NO) return;
  int r = i / NO, c = i - r*NO;
  float acc = b2[c];
  const float* t1 = st1 + (size_t)r*DD;
  for (int k=0; k<DD; ++k) acc += t1[k]*w2T[k*NO + c];
  o[i] = acc;
}

// ---------- Set2Set ----------
__global__ void k_qvec(const float* __restrict__ bih, const float* __restrict__ bhh, float* __restrict__ qv){
  int g = threadIdx.x;
  float gi = bih[g] + bhh[g];
  float gg = bih[128+g] + bhh[128+g];
  float go = bih[192+g] + bhh[192+g];
  float c = sg(gi)*tanhf(gg);
  qv[g] = sg(go)*tanhf(c);
}
__global__ __launch_bounds__(256) void k_e(const float* __restrict__ h, const float* __restrict__ qv,
                    const int* __restrict__ batch, float* __restrict__ evec, unsigned* __restrict__ emax){
  int n = (blockIdx.x*blockDim.x + threadIdx.x) >> 6;
  int lane = threadIdx.x & 63;
  if (n >= NN) return;
  float p = h[(size_t)n*DD + lane] * qv[lane];
  #pragma unroll
  for (int off=32; off; off>>=1) p += __shfl_xor(p, off);
  if (lane == 0){
    evec[n] = p;
    atomicMax(&emax[batch[n]], fenc(p));
  }
}
__global__ __launch_bounds__(256) void k_gsum(const float* __restrict__ h, const float* __restrict__ evec,
                       const unsigned* __restrict__ emax, const int* __restrict__ gptr,
                       float* __restrict__ rvec){
  int g = (blockIdx.x*blockDim.x + threadIdx.x) >> 6;
  int lane = threadIdx.x & 63;
  if (g >= NGG) return;
  int a = gptr[g], b = gptr[g+1];
  if (a >= b){ rvec[(size_t)g*DD + lane] = 0.f; return; }
  float m = fdec(emax[g]);
  float s = 0.f, vacc = 0.f;
  for (int n=a; n<b; ++n){
    float ex = expf(evec[n] - m);
    s += ex;
    vacc += ex * h[(size_t)n*DD + lane];
  }
  rvec[(size_t)g*DD + lane] = vacc / s;
}
__global__ __launch_bounds__(256) void k_gout(const float* __restrict__ qv, const float* __restrict__ rvec,
                       const float* __restrict__ lw, const float* __restrict__ lb, float* __restrict__ o){
  int t = blockIdx.x*blockDim.x + threadIdx.x;
  if (t >= NGG*2) return;
  int g = t >> 1, c = t & 1;
  float acc = lb[c];
  for (int j=0; j<DD; ++j) acc += qv[j]*lw[c*128 + j];
  for (int j=0; j<DD; ++j) acc += rvec[(size_t)g*DD + j]*lw[c*128 + 64 + j];
  o[g*2 + c] = acc;
}

// ---------- host ----------
extern "C" void kernel_launch(void* const* d_in, const int* in_sizes, int n_in,
                              void* d_out_, int out_size, void* d_ws, size_t ws_size,
                              hipStream_t stream){
  const float* x        = (const float*)d_in[0];
  const int*   ei       = (const int*)d_in[1];
  const float* eattr    = (const float*)d_in[2];
  const int*   jbidx    = (const int*)d_in[3];
  const int*   stidx    = (const int*)d_in[4];
  const int*   batch    = (const int*)d_in[5];
  const float* lin0_w   = (const float*)d_in[6];
  const float* lin0_b   = (const float*)d_in[7];
  const float* net1_w   = (const float*)d_in[8];
  const float* net1_b   = (const float*)d_in[9];
  const float* net2_w   = (const float*)d_in[10];
  const float* net2_b   = (const float*)d_in[11];
  const float* conv_root= (const float*)d_in[12];
  const float* conv_b   = (const float*)d_in[13];
  const float* gru_wih  = (const float*)d_in[14];
  const float* gru_whh  = (const float*)d_in[15];
  const float* gru_bih  = (const float*)d_in[16];
  const float* gru_bhh  = (const float*)d_in[17];
  const float* n2s_w1   = (const float*)d_in[18];
  const float* n2s_b1   = (const float*)d_in[19];
  const float* n2s_w2   = (const float*)d_in[20];
  const float* n2s_b2   = (const float*)d_in[21];
  const float* n2j_w1   = (const float*)d_in[22];
  const float* n2j_b1   = (const float*)d_in[23];
  const float* n2j_w2   = (const float*)d_in[24];
  const float* n2j_b2   = (const float*)d_in[25];
  const float* lstm_bih = (const float*)d_in[28];
  const float* lstm_bhh = (const float*)d_in[29];
  const float* lout_w   = (const float*)d_in[30];
  const float* lout_b   = (const float*)d_in[31];
  float* out = (float*)d_out_;

  const int* src = ei;
  const int* dst = ei + NE;

  char* ws = (char*)d_ws;
  size_t off = 0;
  auto alloc = [&](size_t bytes)->void*{
    void* p = ws + off; off = (off + bytes + 255) & ~(size_t)255; return p;
  };
  float* h    = (float*)alloc((size_t)NN*DD*4);
  float* msgbuf = (float*)alloc((size_t)(NE+1)*DD*4);
  unsigned short* hbf = (unsigned short*)alloc((size_t)NPAD*DD*2);
  unsigned short* e1s = (unsigned short*)alloc((size_t)(NE+16)*DD*2);
  unsigned short* w2t = (unsigned short*)alloc((size_t)W2T_ELEMS*2);
  unsigned short* wgru = (unsigned short*)alloc((size_t)WG_ELEMS*2);
  // ---- zeroed group (one memset) ----
  int* degS   = (int*)alloc((size_t)NPAD*4);
  int* cnt    = (int*)alloc((size_t)NPAD*4);
  int* degD   = (int*)alloc((size_t)NPAD*4);
  int* cntD   = (int*)alloc((size_t)NPAD*4);
  int* ghist  = (int*)alloc((size_t)NGG*4);
  unsigned* emax = (unsigned*)alloc((size_t)NGG*4);
  char* zend = ws + off;
  // ---- rest ----
  int* rowptr  = (int*)alloc((size_t)(NPAD+1)*4);
  int* rowptrD = (int*)alloc((size_t)(NPAD+1)*4);
  int* gptr    = (int*)alloc((size_t)(NGG+1)*4);
  int* sEid   = (int*)alloc((size_t)NE*4);
  int* sDpos  = (int*)alloc((size_t)NE*4);
  float* invd = (float*)alloc((size_t)NN*4);
  float* w1jT = (float*)alloc((size_t)DD*DD*4);
  float* w1sT = (float*)alloc((size_t)DD*DD*4);
  float* w2sT = (float*)alloc((size_t)DD*NO*4);
  float* evec = (float*)alloc((size_t)NN*4);
  float* rvec  = (float*)alloc((size_t)NGG*DD*4);
  float* qv    = (float*)alloc((size_t)DD*4);
  float* jtmp  = (float*)alloc((size_t)NJ*2*4);
  float* st1   = (float*)alloc((size_t)NS*DD*4);

  hipFuncSetAttribute((const void*)k_fused8, hipFuncAttributeMaxDynamicSharedMemorySize, LDSB);

  // ---- setup (5 kernels + 1 memset) ----
  hipMemsetAsync(degS, 0, (size_t)(zend - (char*)degS), stream);
  k_setup<<<SB6, 256, 0, stream>>>(x, lin0_w, lin0_b, h, hbf,
                                   net2_w, net2_b, w2t,
                                   conv_root, gru_wih, gru_whh, wgru,
                                   n2j_w1, w1jT, n2s_w1, w1sT, n2s_w2, w2sT);
  k_hist2<<<489, 256, 0, stream>>>(src, dst, degS, degD, batch, ghist);
  k_scan2<<<1, 1024, 0, stream>>>(degS, degD, rowptr, rowptrD, invd, ghist, gptr);
  k_scatter<<<391, 256, 0, stream>>>(src, dst, rowptr, cnt, rowptrD, cntD, sEid, sDpos);
  k_e1s<<<25004, 256, 0, stream>>>(eattr, net1_w, net1_b, sEid, e1s);

  // ---- 6 message-passing + GRU iterations ----
  for (int it=0; it<6; ++it){
    k_fused8<<<TOTBLK, 1024, LDSB, stream>>>(w2t, hbf, e1s, sDpos, rowptr, msgbuf);
    k_gru<<<NBLK, 256, 0, stream>>>(h, hbf, msgbuf, rowptrD, invd, wgru, conv_b, gru_bih, gru_bhh);
  }

  // ---- heads ----
  k_jbond<<<512, 256, 0, stream>>>(h, jbidx, w1jT, n2j_b1, n2j_w2, n2j_b2, jtmp);
  k_jmean<<<4, 256, 0, stream>>>(jtmp, out + NGG*2 + NS*NO);
  k_stem1<<<512, 256, 0, stream>>>(h, stidx, w1sT, n2s_b1, st1);
  k_stem2<<<840, 256, 0, stream>>>(st1, w2sT, n2s_b2, out + NGG*2);

  // ---- Set2Set ----
  k_qvec<<<1, 64, 0, stream>>>(lstm_bih, lstm_bhh, qv);
  k_e<<<6250, 256, 0, stream>>>(h, qv, batch, evec, emax);
  k_gsum<<<128, 256, 0, stream>>>(h, evec, emax, gptr, rvec);
  k_gout<<<4, 256, 0, stream>>>(qv, rvec, lout_w, lout_b, out);
}

// Round 16
// 627.304 us; speedup vs baseline: 1.0382x; 1.0382x over previous
//
#include <hip/hip_runtime.h>
#include <hip/hip_bf16.h>
#include <stdint.h>
#include <stddef.h>

#define NN 25000     // nodes
#define NPAD 25008   // 1563*16
#define NBLK 1563    // node blocks of 16
#define NE 100000    // edges
#define FEAT 16
#define DD 64
#define NGG 512
#define NJ 1024
#define NS 2048
#define NO 105
#define SLOPE 0.01f
#define NQ 4         // o-quarters
#define TPQ 65       // tiles per quarter: 64 W-tiles + 1 bias tile
#define W2T_ELEMS (NQ*TPQ*1024)   // 266240 bf16
#define NSTRIDE 2080 // bytes per node in LDS
#define LDSB (16*NSTRIDE)         // 33280
#define WG_TILES 28
#define WG_ELEMS (WG_TILES*1024)
#define TOTBLK (NBLK*NQ)          // 6252

typedef short bf8 __attribute__((ext_vector_type(8)));   // 8 bf16 raw bits (4 VGPR)
typedef float f32x4 __attribute__((ext_vector_type(4)));

__device__ __forceinline__ float lk(float v){ return v > 0.f ? v : SLOPE*v; }
__device__ __forceinline__ unsigned short f2bf(float f){
  __hip_bfloat16 b = __float2bfloat16(f);
  union { __hip_bfloat16 b; unsigned short u; } c; c.b = b; return c.u;
}
__device__ __forceinline__ float bf2f(unsigned short u){ return __uint_as_float(((unsigned int)u)<<16); }
__device__ __forceinline__ float sg(float x){ return 1.f/(1.f+expf(-x)); }
__device__ __forceinline__ unsigned fenc(float f){ unsigned u = __float_as_uint(f); return (u & 0x80000000u) ? ~u : (u | 0x80000000u); }
__device__ __forceinline__ float fdec(unsigned k){ unsigned u = (k & 0x80000000u) ? (k ^ 0x80000000u) : ~k; return __uint_as_float(u); }

// ---------- merged setup kernel: blockIdx ranges select role ----------
#define SB1 6252
#define SB2 7292
#define SB3 7404
#define SB4 7420
#define SB5 7436
#define SB6 7463
__global__ __launch_bounds__(256) void k_setup(const float* __restrict__ x, const float* __restrict__ l0w,
      const float* __restrict__ l0b, float* __restrict__ h, unsigned short* __restrict__ hbf,
      const float* __restrict__ w2, const float* __restrict__ b2, unsigned short* __restrict__ w2t,
      const float* __restrict__ cr, const float* __restrict__ wih, const float* __restrict__ whh,
      unsigned short* __restrict__ wgru,
      const float* __restrict__ jw1, float* __restrict__ w1jT,
      const float* __restrict__ sw1, float* __restrict__ w1sT,
      const float* __restrict__ sw2, float* __restrict__ w2sT){
  int bid = blockIdx.x, tid = threadIdx.x;
  if (bid < SB1){
    int wid = (bid*256 + tid) >> 6;
    int lane = tid & 63;
    if (wid >= NPAD) return;
    if (wid >= NN){ hbf[(size_t)wid*DD + lane] = 0; return; }
    float xv = lane < FEAT ? x[wid*FEAT + lane] : 0.f;
    float acc = l0b[lane];
    #pragma unroll
    for (int f=0; f<FEAT; ++f) acc += __shfl(xv, f) * l0w[lane*FEAT + f];
    float v = lk(acc);
    h[wid*DD + lane] = v;
    hbf[(size_t)wid*DD + lane] = f2bf(v);
  } else if (bid < SB2){
    int u = (bid-SB1)*256 + tid;
    if (u >= W2T_ELEMS) return;
    int j = u & 7;
    int lane = (u >> 3) & 63;
    int kc = (u >> 9) & 1;
    int tg = u >> 10;
    int oq = tg / TPQ, tq = tg - oq*TPQ;
    int r16 = lane & 15, kg = lane >> 4;
    int i = kc*32 + kg*8 + j;
    float v;
    if (tq < 64) v = w2[(size_t)i*4096 + (oq*1024 + tq*16 + r16)];
    else         v = b2[i*64 + oq*16 + r16];
    w2t[u] = f2bf(v);
  } else if (bid < SB3){
    int u = (bid-SB2)*256 + tid;
    if (u >= WG_ELEMS) return;
    int j = u & 7;
    int lane = (u >> 3) & 63;
    int kc = (u >> 9) & 1;
    int t = u >> 10;
    int r16 = lane & 15, kg = lane >> 4;
    int i = kc*32 + kg*8 + j;
    float v;
    if (t < 4)       v = cr[(size_t)i*DD + t*16 + r16];
    else if (t < 16) v = wih[(size_t)((t-4)*16 + r16)*DD + i];
    else             v = whh[(size_t)((t-16)*16 + r16)*DD + i];
    wgru[u] = f2bf(v);
  } else if (bid < SB4){
    int i = (bid-SB3)*256 + tid;
    if (i < DD*DD){ int r = i >> 6, c = i & 63; w1jT[c*DD + r] = jw1[i]; }
  } else if (bid < SB5){
    int i = (bid-SB4)*256 + tid;
    if (i < DD*DD){ int r = i >> 6, c = i & 63; w1sT[c*DD + r] = sw1[i]; }
  } else {
    int i = (bid-SB5)*256 + tid;
    if (i < NO*DD){ int r = i / DD, c = i - r*DD; w2sT[c*NO + r] = sw2[i]; }
  }
}

// ---------- merged histograms ----------
__global__ __launch_bounds__(256) void k_hist2(const int* __restrict__ src, const int* __restrict__ dst,
                                               int* __restrict__ degS, int* __restrict__ degD,
                                               const int* __restrict__ batch, int* __restrict__ ghist){
  int bid = blockIdx.x;
  if (bid < 391){
    int e = bid*256 + threadIdx.x;
    if (e < NE){ atomicAdd(&degS[src[e]], 1); atomicAdd(&degD[dst[e]], 1); }
  } else {
    int n = (bid-391)*256 + threadIdx.x;
    if (n < NN) atomicAdd(&ghist[batch[n]], 1);
  }
}

// ---------- merged scans ----------
__global__ __launch_bounds__(1024) void k_scan2(const int* __restrict__ degS, const int* __restrict__ degD,
        int* __restrict__ rowptr, int* __restrict__ rowptrD, float* __restrict__ invd,
        const int* __restrict__ ghist, int* __restrict__ gptr){
  __shared__ int wsA[16], wsB[16];
  __shared__ int baseA, baseB;
  int tid = threadIdx.x, lane = tid & 63, wv = tid >> 6;
  if (tid == 0){ baseA = 0; baseB = 0; rowptr[0] = 0; rowptrD[0] = 0; }
  __syncthreads();
  for (int c0 = 0; c0 < NPAD; c0 += 1024){
    int i = c0 + tid;
    int vA = (i < NPAD) ? degS[i] : 0;
    int vB = (i < NPAD) ? degD[i] : 0;
    if (i < NN) invd[i] = vB > 0 ? 1.f/(float)vB : 0.f;
    int sA = vA, sB = vB;
    #pragma unroll
    for (int off=1; off<64; off<<=1){
      int tA = __shfl_up(sA, off), tB = __shfl_up(sB, off);
      if (lane >= off){ sA += tA; sB += tB; }
    }
    if (lane == 63){ wsA[wv] = sA; wsB[wv] = sB; }
    __syncthreads();
    if (wv == 0 && lane < 16){
      int w = wsA[lane];
      #pragma unroll
      for (int off=1; off<16; off<<=1){ int t = __shfl_up(w, off); if (lane >= off) w += t; }
      wsA[lane] = w;
    }
    if (wv == 1 && lane < 16){
      int w = wsB[lane];
      #pragma unroll
      for (int off=1; off<16; off<<=1){ int t = __shfl_up(w, off); if (lane >= off) w += t; }
      wsB[lane] = w;
    }
    __syncthreads();
    int wbA = wv ? wsA[wv-1] : 0;
    int wbB = wv ? wsB[wv-1] : 0;
    if (i < NPAD){ rowptr[i+1] = baseA + wbA + sA; rowptrD[i+1] = baseB + wbB + sB; }
    __syncthreads();
    if (tid == 0){ baseA += wsA[15]; baseB += wsB[15]; }
    __syncthreads();
  }
  int s = (tid < 512) ? ghist[tid] : 0;
  #pragma unroll
  for (int off=1; off<64; off<<=1){ int t = __shfl_up(s, off); if (lane >= off) s += t; }
  if (tid < 512 && lane == 63) wsA[wv] = s;
  __syncthreads();
  if (wv == 0 && lane < 8){
    int w = wsA[lane];
    #pragma unroll
    for (int off=1; off<8; off<<=1){ int t = __shfl_up(w, off); if (lane >= off) w += t; }
    wsA[lane] = w;
  }
  __syncthreads();
  if (tid < 512){
    int wb = wv ? wsA[wv-1] : 0;
    gptr[tid+1] = wb + s;
    if (tid == 0) gptr[0] = 0;
  }
}

// scatter: src-sorted pos gets edge id + dst-sorted position
__global__ __launch_bounds__(256) void k_scatter(const int* __restrict__ src, const int* __restrict__ dst,
                         const int* __restrict__ rowptr, int* __restrict__ cnt,
                         const int* __restrict__ rowptrD, int* __restrict__ cntD,
                         int* __restrict__ sEid, int* __restrict__ sDpos){
  int e = blockIdx.x*blockDim.x + threadIdx.x;
  if (e >= NE) return;
  int s = src[e], d = dst[e];
  int pos = rowptr[s] + atomicAdd(&cnt[s], 1);
  sEid[pos] = e;
  sDpos[pos] = rowptrD[d] + atomicAdd(&cntD[d], 1);
}

// e1 sorted, wave-per-position; pad rows zeroed; ea row read is a wave-broadcast
__global__ __launch_bounds__(256) void k_e1s(const float* __restrict__ ea, const float* __restrict__ w,
                     const float* __restrict__ b, const int* __restrict__ sEid,
                     unsigned short* __restrict__ e1s){
  int pos = (blockIdx.x*blockDim.x + threadIdx.x) >> 6;
  int lane = threadIdx.x & 63;
  if (pos >= NE + 16) return;
  if (pos >= NE){ e1s[(size_t)pos*DD + lane] = 0; return; }
  int e = sEid[pos];
  const float* er = ea + (size_t)e*4;
  float a0 = er[0], a1 = er[1], a2 = er[2], a3 = er[3];
  const float* wr = w + lane*4;
  float acc = b[lane] + a0*wr[0] + a1*wr[1] + a2*wr[2] + a3*wr[3];
  e1s[(size_t)pos*DD + lane] = f2bf(lk(acc));
}

// ---------- fused message kernel (round-14 structure; bf16 msgbuf) ----------
__global__ __launch_bounds__(512) void k_fused8(const unsigned short* __restrict__ w2t,
                                                const unsigned short* __restrict__ hbf,
                                                const unsigned short* __restrict__ e1s,
                                                const int* __restrict__ sDpos,
                                                const int* __restrict__ rowptr,
                                                unsigned short* __restrict__ msgbuf){
  extern __shared__ char smem[];
  int lane = threadIdx.x & 63;
  int wv   = threadIdx.x >> 6;           // 0..7
  int xcd = blockIdx.x & 7, q = blockIdx.x >> 3;
  int g = xcd*781 + (xcd < 4 ? xcd : 4) + q;
  int n0 = (g >> 2) * 16;
  int oq = g & 3;
  int r16 = lane & 15, kg = lane >> 4;

  const unsigned short* hp = hbf + (size_t)(n0 + r16)*DD;
  bf8 bh0 = *(const bf8*)(hp + kg*8);
  bf8 bh1 = *(const bf8*)(hp + 32 + kg*8);

  // phase A
  {
    const unsigned short* wq = w2t + (size_t)oq*TPQ*1024;
    int nsw = r16 & 7;
    for (int tq = wv; tq < TPQ; tq += 8){
      const unsigned short* wp = wq + (size_t)tq*1024;
      bf8 a0 = *(const bf8*)(wp + lane*8);
      bf8 a1 = *(const bf8*)(wp + 512 + lane*8);
      f32x4 acc = {0.f,0.f,0.f,0.f};
      acc = __builtin_amdgcn_mfma_f32_16x16x32_bf16(a0, bh0, acc, 0,0,0);
      acc = __builtin_amdgcn_mfma_f32_16x16x32_bf16(a1, bh1, acc, 0,0,0);
      unsigned u0 = (unsigned)f2bf(acc[0]) | ((unsigned)f2bf(acc[1]) << 16);
      unsigned u1 = (unsigned)f2bf(acc[2]) | ((unsigned)f2bf(acc[3]) << 16);
      unsigned long long ull = (unsigned long long)u0 | ((unsigned long long)u1 << 32);
      if (tq < 64){
        int o_rel = tq >> 2;
        int s = ((tq & 3) << 1) + (kg >> 1);
        int slot = s ^ (o_rel & 7) ^ nsw;
        *(unsigned long long*)(smem + (size_t)r16*NSTRIDE + o_rel*128 + (slot<<4) + ((kg & 1)*8)) = ull;
      } else {
        *(unsigned long long*)(smem + (size_t)r16*NSTRIDE + 2048 + kg*8) = ull;
      }
    }
  }
  __syncthreads();

  // phase B (round-11 proven form; bf16 stores)
  #pragma unroll
  for (int s2 = 0; s2 < 2; ++s2){
    int nl = wv + 8*s2;
    int node = n0 + nl;
    int estart = rowptr[node], eend = rowptr[node + 1];
    const char* ab = smem + (size_t)nl*NSTRIDE;
    int nsw = nl & 7;
    int slot0 = (kg) ^ (r16 & 7) ^ nsw;
    int slot1 = (4 + kg) ^ (r16 & 7) ^ nsw;
    bf8 B0 = *(const bf8*)(ab + r16*128 + (slot0<<4));
    bf8 B1 = *(const bf8*)(ab + r16*128 + (slot1<<4));
    float bias = bf2f(*(const unsigned short*)(ab + 2048 + r16*2));
    for (int eg = estart; eg < eend; eg += 16){
      bf8 af0 = {0,0,0,0,0,0,0,0}, af1 = {0,0,0,0,0,0,0,0};
      int er = eg + r16;
      if (er < eend){
        af0 = *(const bf8*)(e1s + (size_t)er*DD + kg*8);
        af1 = *(const bf8*)(e1s + (size_t)er*DD + 32 + kg*8);
      }
      int ebase = eg + kg*4;
      int dp[4];
      #pragma unroll
      for (int j=0; j<4; ++j){
        int e = ebase + j;
        dp[j] = (e < eend) ? sDpos[e] : -1;
      }
      f32x4 acc = {0.f,0.f,0.f,0.f};
      acc = __builtin_amdgcn_mfma_f32_16x16x32_bf16(af0, B0, acc, 0,0,0);
      acc = __builtin_amdgcn_mfma_f32_16x16x32_bf16(af1, B1, acc, 0,0,0);
      #pragma unroll
      for (int j=0; j<4; ++j){
        if (dp[j] >= 0)
          msgbuf[(size_t)dp[j]*DD + oq*16 + r16] = f2bf(acc[j] + bias);
      }
    }
  }
}

// ---------- MFMA GRU: block = 16 nodes, 4 waves (bf16 msgbuf reads) ----------
__global__ __launch_bounds__(256) void k_gru(float* __restrict__ h, unsigned short* __restrict__ hbf,
                      const unsigned short* __restrict__ msgbuf, const int* __restrict__ rowptrD,
                      const float* __restrict__ invd,
                      const unsigned short* __restrict__ wgru,
                      const float* __restrict__ cb,
                      const float* __restrict__ bih, const float* __restrict__ bhh){
  __shared__ float msum[16*68];
  __shared__ unsigned short mbf[16*64];
  __shared__ float iv[16];
  int tid = threadIdx.x;
  int lane = tid & 63, wv = tid >> 6;
  int n0 = blockIdx.x * 16;
  int r16 = lane & 15, kg = lane >> 4;

  const unsigned short* hp = hbf + (size_t)(n0 + r16)*DD;
  bf8 af0 = *(const bf8*)(hp + kg*8);
  bf8 af1 = *(const bf8*)(hp + 32 + kg*8);

  if (tid < 16) iv[tid] = (n0 + tid < NN) ? invd[n0 + tid] : 0.f;
  #pragma unroll
  for (int q=0; q<4; ++q){
    int nl = wv*4 + q;
    int node = n0 + nl;
    float ms = 0.f;
    if (node < NN){
      int pa = rowptrD[node], pb = rowptrD[node+1];
      for (int p=pa; p<pb; ++p) ms += bf2f(msgbuf[(size_t)p*DD + lane]);
    }
    msum[nl*68 + lane] = ms;
  }
  __syncthreads();

  int o = wv*16 + r16;
  {
    const unsigned short* tp = wgru + (size_t)wv*1024;
    bf8 bc0 = *(const bf8*)(tp + lane*8);
    bf8 bc1 = *(const bf8*)(tp + 512 + lane*8);
    f32x4 cacc = {0.f,0.f,0.f,0.f};
    cacc = __builtin_amdgcn_mfma_f32_16x16x32_bf16(af0, bc0, cacc, 0,0,0);
    cacc = __builtin_amdgcn_mfma_f32_16x16x32_bf16(af1, bc1, cacc, 0,0,0);
    float cbo = cb[o];
    int gi_gran = o >> 3;
    #pragma unroll
    for (int j=0; j<4; ++j){
      int nl = kg*4 + j;
      float mval = lk(msum[nl*68 + o]*iv[nl] + cacc[j] + cbo);
      int swz = gi_gran ^ (nl & 7);
      *(unsigned short*)((char*)mbf + nl*128 + (swz<<4) + (o&7)*2) = f2bf(mval);
    }
  }
  __syncthreads();

  bf8 am0 = *(const bf8*)((char*)mbf + r16*128 + (((kg) ^ (r16 & 7))<<4));
  bf8 am1 = *(const bf8*)((char*)mbf + r16*128 + (((4 + kg) ^ (r16 & 7))<<4));

  f32x4 gi_r={0,0,0,0}, gi_z={0,0,0,0}, gi_n={0,0,0,0};
  f32x4 gh_r={0,0,0,0}, gh_z={0,0,0,0}, gh_n={0,0,0,0};
  {
    const unsigned short* t0 = wgru + (size_t)(4 + 0*4 + wv)*1024;
    const unsigned short* t1 = wgru + (size_t)(4 + 1*4 + wv)*1024;
    const unsigned short* t2 = wgru + (size_t)(4 + 2*4 + wv)*1024;
    const unsigned short* u0 = wgru + (size_t)(16 + 0*4 + wv)*1024;
    const unsigned short* u1 = wgru + (size_t)(16 + 1*4 + wv)*1024;
    const unsigned short* u2 = wgru + (size_t)(16 + 2*4 + wv)*1024;
    gi_r = __builtin_amdgcn_mfma_f32_16x16x32_bf16(am0, *(const bf8*)(t0 + lane*8), gi_r, 0,0,0);
    gi_r = __builtin_amdgcn_mfma_f32_16x16x32_bf16(am1, *(const bf8*)(t0 + 512 + lane*8), gi_r, 0,0,0);
    gi_z = __builtin_amdgcn_mfma_f32_16x16x32_bf16(am0, *(const bf8*)(t1 + lane*8), gi_z, 0,0,0);
    gi_z = __builtin_amdgcn_mfma_f32_16x16x32_bf16(am1, *(const bf8*)(t1 + 512 + lane*8), gi_z, 0,0,0);
    gi_n = __builtin_amdgcn_mfma_f32_16x16x32_bf16(am0, *(const bf8*)(t2 + lane*8), gi_n, 0,0,0);
    gi_n = __builtin_amdgcn_mfma_f32_16x16x32_bf16(am1, *(const bf8*)(t2 + 512 + lane*8), gi_n, 0,0,0);
    gh_r = __builtin_amdgcn_mfma_f32_16x16x32_bf16(af0, *(const bf8*)(u0 + lane*8), gh_r, 0,0,0);
    gh_r = __builtin_amdgcn_mfma_f32_16x16x32_bf16(af1, *(const bf8*)(u0 + 512 + lane*8), gh_r, 0,0,0);
    gh_z = __builtin_amdgcn_mfma_f32_16x16x32_bf16(af0, *(const bf8*)(u1 + lane*8), gh_z, 0,0,0);
    gh_z = __builtin_amdgcn_mfma_f32_16x16x32_bf16(af1, *(const bf8*)(u1 + 512 + lane*8), gh_z, 0,0,0);
    gh_n = __builtin_amdgcn_mfma_f32_16x16x32_bf16(af0, *(const bf8*)(u2 + lane*8), gh_n, 0,0,0);
    gh_n = __builtin_amdgcn_mfma_f32_16x16x32_bf16(af1, *(const bf8*)(u2 + 512 + lane*8), gh_n, 0,0,0);
  }
  float bi0 = bih[o], bi1 = bih[64+o], bi2 = bih[128+o];
  float bh0 = bhh[o], bh1 = bhh[64+o], bh2 = bhh[128+o];
  #pragma unroll
  for (int j=0; j<4; ++j){
    int node = n0 + kg*4 + j;
    if (node < NN){
      size_t idx = (size_t)node*DD + o;
      float hv = h[idx];
      float r = sg(gi_r[j] + bi0 + gh_r[j] + bh0);
      float z = sg(gi_z[j] + bi1 + gh_z[j] + bh1);
      float nn = tanhf(gi_n[j] + bi2 + r*(gh_n[j] + bh2));
      float nh = (1.f - z)*nn + z*hv;
      h[idx] = nh;
      hbf[idx] = f2bf(nh);
    }
  }
}

// ---------- heads ----------
__global__ __launch_bounds__(256) void k_jbond(const float* __restrict__ h, const int* __restrict__ idx,
                        const float* __restrict__ w1T, const float* __restrict__ b1,
                        const float* __restrict__ w2, const float* __restrict__ b2,
                        float* __restrict__ jtmp){
  int wid = (blockIdx.x*blockDim.x + threadIdx.x) >> 6;
  int lane = threadIdx.x & 63;
  if (wid >= NJ*2) return;
  int a = idx[wid];
  float f = h[(size_t)a*DD + lane];
  float acc = b1[lane];
  for (int i=0; i<DD; ++i) acc += __shfl(f, i) * w1T[i*DD + lane];
  float p = lk(acc) * w2[lane];
  #pragma unroll
  for (int off=32; off; off>>=1) p += __shfl_xor(p, off);
  if (lane == 0) jtmp[wid] = p + b2[0];
}
__global__ __launch_bounds__(256) void k_jmean(const float* __restrict__ jtmp, float* __restrict__ o){
  int j = blockIdx.x*blockDim.x + threadIdx.x;
  if (j < NJ) o[j] = 0.5f*(jtmp[2*j] + jtmp[2*j+1]);
}
__global__ __launch_bounds__(256) void k_stem1(const float* __restrict__ h, const int* __restrict__ idx,
                        const float* __restrict__ w1T, const float* __restrict__ b1,
                        float* __restrict__ st1){
  int wid = (blockIdx.x*blockDim.x + threadIdx.x) >> 6;
  int lane = threadIdx.x & 63;
  if (wid >= NS) return;
  int a = idx[wid];
  float f = h[(size_t)a*DD + lane];
  float acc = b1[lane];
  for (int i=0; i<DD; ++i) acc += __shfl(f, i) * w1T[i*DD + lane];
  st1[(size_t)wid*DD + lane] = lk(acc);
}
__global__ __launch_bounds__(256) void k_stem2(const float* __restrict__ st1, const float* __restrict__ w2T,
                        const float* __restrict__ b2, float* __restrict__ o){
  int i = blockIdx.x*blockDim.x + threadIdx.x;
  if (i >= NS*NO) return;
  int r = i / NO, c = i - r*NO;
  float acc = b2[c];
  const float* t1 = st1 + (size_t)r*DD;
  for (int k=0; k<DD; ++k) acc += t1[k]*w2T[k*NO + c];
  o[i] = acc;
}

// ---------- Set2Set ----------
__global__ void k_qvec(const float* __restrict__ bih, const float* __restrict__ bhh, float* __restrict__ qv){
  int g = threadIdx.x;
  float gi = bih[g] + bhh[g];
  float gg = bih[128+g] + bhh[128+g];
  float go = bih[192+g] + bhh[192+g];
  float c = sg(gi)*tanhf(gg);
  qv[g] = sg(go)*tanhf(c);
}
__global__ __launch_bounds__(256) void k_e(const float* __restrict__ h, const float* __restrict__ qv,
                    const int* __restrict__ batch, float* __restrict__ evec, unsigned* __restrict__ emax){
  int n = (blockIdx.x*blockDim.x + threadIdx.x) >> 6;
  int lane = threadIdx.x & 63;
  if (n >= NN) return;
  float p = h[(size_t)n*DD + lane] * qv[lane];
  #pragma unroll
  for (int off=32; off; off>>=1) p += __shfl_xor(p, off);
  if (lane == 0){
    evec[n] = p;
    atomicMax(&emax[batch[n]], fenc(p));
  }
}
__global__ __launch_bounds__(256) void k_gsum(const float* __restrict__ h, const float* __restrict__ evec,
                       const unsigned* __restrict__ emax, const int* __restrict__ gptr,
                       float* __restrict__ rvec){
  int g = (blockIdx.x*blockDim.x + threadIdx.x) >> 6;
  int lane = threadIdx.x & 63;
  if (g >= NGG) return;
  int a = gptr[g], b = gptr[g+1];
  if (a >= b){ rvec[(size_t)g*DD + lane] = 0.f; return; }
  float m = fdec(emax[g]);
  float s = 0.f, vacc = 0.f;
  for (int n=a; n<b; ++n){
    float ex = expf(evec[n] - m);
    s += ex;
    vacc += ex * h[(size_t)n*DD + lane];
  }
  rvec[(size_t)g*DD + lane] = vacc / s;
}
__global__ __launch_bounds__(256) void k_gout(const float* __restrict__ qv, const float* __restrict__ rvec,
                       const float* __restrict__ lw, const float* __restrict__ lb, float* __restrict__ o){
  int t = blockIdx.x*blockDim.x + threadIdx.x;
  if (t >= NGG*2) return;
  int g = t >> 1, c = t & 1;
  float acc = lb[c];
  for (int j=0; j<DD; ++j) acc += qv[j]*lw[c*128 + j];
  for (int j=0; j<DD; ++j) acc += rvec[(size_t)g*DD + j]*lw[c*128 + 64 + j];
  o[g*2 + c] = acc;
}

// ---------- host ----------
extern "C" void kernel_launch(void* const* d_in, const int* in_sizes, int n_in,
                              void* d_out_, int out_size, void* d_ws, size_t ws_size,
                              hipStream_t stream){
  const float* x        = (const float*)d_in[0];
  const int*   ei       = (const int*)d_in[1];
  const float* eattr    = (const float*)d_in[2];
  const int*   jbidx    = (const int*)d_in[3];
  const int*   stidx    = (const int*)d_in[4];
  const int*   batch    = (const int*)d_in[5];
  const float* lin0_w   = (const float*)d_in[6];
  const float* lin0_b   = (const float*)d_in[7];
  const float* net1_w   = (const float*)d_in[8];
  const float* net1_b   = (const float*)d_in[9];
  const float* net2_w   = (const float*)d_in[10];
  const float* net2_b   = (const float*)d_in[11];
  const float* conv_root= (const float*)d_in[12];
  const float* conv_b   = (const float*)d_in[13];
  const float* gru_wih  = (const float*)d_in[14];
  const float* gru_whh  = (const float*)d_in[15];
  const float* gru_bih  = (const float*)d_in[16];
  const float* gru_bhh  = (const float*)d_in[17];
  const float* n2s_w1   = (const float*)d_in[18];
  const float* n2s_b1   = (const float*)d_in[19];
  const float* n2s_w2   = (const float*)d_in[20];
  const float* n2s_b2   = (const float*)d_in[21];
  const float* n2j_w1   = (const float*)d_in[22];
  const float* n2j_b1   = (const float*)d_in[23];
  const float* n2j_w2   = (const float*)d_in[24];
  const float* n2j_b2   = (const float*)d_in[25];
  const float* lstm_bih = (const float*)d_in[28];
  const float* lstm_bhh = (const float*)d_in[29];
  const float* lout_w   = (const float*)d_in[30];
  const float* lout_b   = (const float*)d_in[31];
  float* out = (float*)d_out_;

  const int* src = ei;
  const int* dst = ei + NE;

  char* ws = (char*)d_ws;
  size_t off = 0;
  auto alloc = [&](size_t bytes)->void*{
    void* p = ws + off; off = (off + bytes + 255) & ~(size_t)255; return p;
  };
  float* h    = (float*)alloc((size_t)NN*DD*4);
  unsigned short* msgbuf = (unsigned short*)alloc((size_t)(NE+1)*DD*2);   // bf16
  unsigned short* hbf = (unsigned short*)alloc((size_t)NPAD*DD*2);
  unsigned short* e1s = (unsigned short*)alloc((size_t)(NE+16)*DD*2);
  unsigned short* w2t = (unsigned short*)alloc((size_t)W2T_ELEMS*2);
  unsigned short* wgru = (unsigned short*)alloc((size_t)WG_ELEMS*2);
  // ---- zeroed group (one memset) ----
  int* degS   = (int*)alloc((size_t)NPAD*4);
  int* cnt    = (int*)alloc((size_t)NPAD*4);
  int* degD   = (int*)alloc((size_t)NPAD*4);
  int* cntD   = (int*)alloc((size_t)NPAD*4);
  int* ghist  = (int*)alloc((size_t)NGG*4);
  unsigned* emax = (unsigned*)alloc((size_t)NGG*4);
  char* zend = ws + off;
  // ---- rest ----
  int* rowptr  = (int*)alloc((size_t)(NPAD+1)*4);
  int* rowptrD = (int*)alloc((size_t)(NPAD+1)*4);
  int* gptr    = (int*)alloc((size_t)(NGG+1)*4);
  int* sEid   = (int*)alloc((size_t)NE*4);
  int* sDpos  = (int*)alloc((size_t)NE*4);
  float* invd = (float*)alloc((size_t)NN*4);
  float* w1jT = (float*)alloc((size_t)DD*DD*4);
  float* w1sT = (float*)alloc((size_t)DD*DD*4);
  float* w2sT = (float*)alloc((size_t)DD*NO*4);
  float* evec = (float*)alloc((size_t)NN*4);
  float* rvec  = (float*)alloc((size_t)NGG*DD*4);
  float* qv    = (float*)alloc((size_t)DD*4);
  float* jtmp  = (float*)alloc((size_t)NJ*2*4);
  float* st1   = (float*)alloc((size_t)NS*DD*4);

  hipFuncSetAttribute((const void*)k_fused8, hipFuncAttributeMaxDynamicSharedMemorySize, LDSB);

  // ---- setup (5 kernels + 1 memset) ----
  hipMemsetAsync(degS, 0, (size_t)(zend - (char*)degS), stream);
  k_setup<<<SB6, 256, 0, stream>>>(x, lin0_w, lin0_b, h, hbf,
                                   net2_w, net2_b, w2t,
                                   conv_root, gru_wih, gru_whh, wgru,
                                   n2j_w1, w1jT, n2s_w1, w1sT, n2s_w2, w2sT);
  k_hist2<<<489, 256, 0, stream>>>(src, dst, degS, degD, batch, ghist);
  k_scan2<<<1, 1024, 0, stream>>>(degS, degD, rowptr, rowptrD, invd, ghist, gptr);
  k_scatter<<<391, 256, 0, stream>>>(src, dst, rowptr, cnt, rowptrD, cntD, sEid, sDpos);
  k_e1s<<<25004, 256, 0, stream>>>(eattr, net1_w, net1_b, sEid, e1s);

  // ---- 6 message-passing + GRU iterations ----
  for (int it=0; it<6; ++it){
    k_fused8<<<TOTBLK, 512, LDSB, stream>>>(w2t, hbf, e1s, sDpos, rowptr, msgbuf);
    k_gru<<<NBLK, 256, 0, stream>>>(h, hbf, msgbuf, rowptrD, invd, wgru, conv_b, gru_bih, gru_bhh);
  }

  // ---- heads ----
  k_jbond<<<512, 256, 0, stream>>>(h, jbidx, w1jT, n2j_b1, n2j_w2, n2j_b2, jtmp);
  k_jmean<<<4, 256, 0, stream>>>(jtmp, out + NGG*2 + NS*NO);
  k_stem1<<<512, 256, 0, stream>>>(h, stidx, w1sT, n2s_b1, st1);
  k_stem2<<<840, 256, 0, stream>>>(st1, w2sT, n2s_b2, out + NGG*2);

  // ---- Set2Set ----
  k_qvec<<<1, 64, 0, stream>>>(lstm_bih, lstm_bhh, qv);
  k_e<<<6250, 256, 0, stream>>>(h, qv, batch, evec, emax);
  k_gsum<<<128, 256, 0, stream>>>(h, evec, emax, gptr, rvec);
  k_gout<<<4, 256, 0, stream>>>(qv, rvec, lout_w, lout_b, out);
}

// Round 17
// 612.441 us; speedup vs baseline: 1.0634x; 1.0243x over previous
//
#include <hip/hip_runtime.h>
#include <hip/hip_bf16.h>
#include <stdint.h>
#include <stddef.h>

#define NN 25000     // nodes
#define NPAD 25008   // 1563*16
#define NBLK 1563    // node blocks of 16
#define NE 100000    // edges
#define FEAT 16
#define DD 64
#define NGG 512
#define NJ 1024
#define NS 2048
#define NO 105
#define SLOPE 0.01f
#define NQ 4         // o-quarters
#define TPQ 65       // tiles per quarter: 64 W-tiles + 1 bias tile
#define W2T_ELEMS (NQ*TPQ*1024)   // 266240 bf16
#define NSTRIDE 2080 // bytes per node in LDS
#define LDSB (16*NSTRIDE)         // 33280
#define WG_TILES 28
#define WG_ELEMS (WG_TILES*1024)
#define TOTBLK (NBLK*NQ)          // 6252

typedef short bf8 __attribute__((ext_vector_type(8)));   // 8 bf16 raw bits (4 VGPR)
typedef float f32x4 __attribute__((ext_vector_type(4)));

__device__ __forceinline__ float lk(float v){ return v > 0.f ? v : SLOPE*v; }
__device__ __forceinline__ unsigned short f2bf(float f){
  __hip_bfloat16 b = __float2bfloat16(f);
  union { __hip_bfloat16 b; unsigned short u; } c; c.b = b; return c.u;
}
__device__ __forceinline__ float bf2f(unsigned short u){ return __uint_as_float(((unsigned int)u)<<16); }
__device__ __forceinline__ float sg(float x){ return 1.f/(1.f+expf(-x)); }
__device__ __forceinline__ unsigned fenc(float f){ unsigned u = __float_as_uint(f); return (u & 0x80000000u) ? ~u : (u | 0x80000000u); }
__device__ __forceinline__ float fdec(unsigned k){ unsigned u = (k & 0x80000000u) ? (k ^ 0x80000000u) : ~k; return __uint_as_float(u); }

// ---------- merged setup kernel: blockIdx ranges select role ----------
#define SB1 6252
#define SB2 7292
#define SB3 7404
#define SB4 7420
#define SB5 7436
#define SB6 7463
__global__ __launch_bounds__(256) void k_setup(const float* __restrict__ x, const float* __restrict__ l0w,
      const float* __restrict__ l0b, float* __restrict__ h, unsigned short* __restrict__ hbf,
      const float* __restrict__ w2, const float* __restrict__ b2, unsigned short* __restrict__ w2t,
      const float* __restrict__ cr, const float* __restrict__ wih, const float* __restrict__ whh,
      unsigned short* __restrict__ wgru,
      const float* __restrict__ jw1, float* __restrict__ w1jT,
      const float* __restrict__ sw1, float* __restrict__ w1sT,
      const float* __restrict__ sw2, float* __restrict__ w2sT){
  int bid = blockIdx.x, tid = threadIdx.x;
  if (bid < SB1){
    int wid = (bid*256 + tid) >> 6;
    int lane = tid & 63;
    if (wid >= NPAD) return;
    if (wid >= NN){ hbf[(size_t)wid*DD + lane] = 0; return; }
    float xv = lane < FEAT ? x[wid*FEAT + lane] : 0.f;
    float acc = l0b[lane];
    #pragma unroll
    for (int f=0; f<FEAT; ++f) acc += __shfl(xv, f) * l0w[lane*FEAT + f];
    float v = lk(acc);
    h[wid*DD + lane] = v;
    hbf[(size_t)wid*DD + lane] = f2bf(v);
  } else if (bid < SB2){
    int u = (bid-SB1)*256 + tid;
    if (u >= W2T_ELEMS) return;
    int j = u & 7;
    int lane = (u >> 3) & 63;
    int kc = (u >> 9) & 1;
    int tg = u >> 10;
    int oq = tg / TPQ, tq = tg - oq*TPQ;
    int r16 = lane & 15, kg = lane >> 4;
    int i = kc*32 + kg*8 + j;
    float v;
    if (tq < 64) v = w2[(size_t)i*4096 + (oq*1024 + tq*16 + r16)];
    else         v = b2[i*64 + oq*16 + r16];
    w2t[u] = f2bf(v);
  } else if (bid < SB3){
    int u = (bid-SB2)*256 + tid;
    if (u >= WG_ELEMS) return;
    int j = u & 7;
    int lane = (u >> 3) & 63;
    int kc = (u >> 9) & 1;
    int t = u >> 10;
    int r16 = lane & 15, kg = lane >> 4;
    int i = kc*32 + kg*8 + j;
    float v;
    if (t < 4)       v = cr[(size_t)i*DD + t*16 + r16];
    else if (t < 16) v = wih[(size_t)((t-4)*16 + r16)*DD + i];
    else             v = whh[(size_t)((t-16)*16 + r16)*DD + i];
    wgru[u] = f2bf(v);
  } else if (bid < SB4){
    int i = (bid-SB3)*256 + tid;
    if (i < DD*DD){ int r = i >> 6, c = i & 63; w1jT[c*DD + r] = jw1[i]; }
  } else if (bid < SB5){
    int i = (bid-SB4)*256 + tid;
    if (i < DD*DD){ int r = i >> 6, c = i & 63; w1sT[c*DD + r] = sw1[i]; }
  } else {
    int i = (bid-SB5)*256 + tid;
    if (i < NO*DD){ int r = i / DD, c = i - r*DD; w2sT[c*NO + r] = sw2[i]; }
  }
}

// ---------- merged histograms ----------
__global__ __launch_bounds__(256) void k_hist2(const int* __restrict__ src, const int* __restrict__ dst,
                                               int* __restrict__ degS, int* __restrict__ degD,
                                               const int* __restrict__ batch, int* __restrict__ ghist){
  int bid = blockIdx.x;
  if (bid < 391){
    int e = bid*256 + threadIdx.x;
    if (e < NE){ atomicAdd(&degS[src[e]], 1); atomicAdd(&degD[dst[e]], 1); }
  } else {
    int n = (bid-391)*256 + threadIdx.x;
    if (n < NN) atomicAdd(&ghist[batch[n]], 1);
  }
}

// ---------- merged scans ----------
__global__ __launch_bounds__(1024) void k_scan2(const int* __restrict__ degS, const int* __restrict__ degD,
        int* __restrict__ rowptr, int* __restrict__ rowptrD, float* __restrict__ invd,
        const int* __restrict__ ghist, int* __restrict__ gptr){
  __shared__ int wsA[16], wsB[16];
  __shared__ int baseA, baseB;
  int tid = threadIdx.x, lane = tid & 63, wv = tid >> 6;
  if (tid == 0){ baseA = 0; baseB = 0; rowptr[0] = 0; rowptrD[0] = 0; }
  __syncthreads();
  for (int c0 = 0; c0 < NPAD; c0 += 1024){
    int i = c0 + tid;
    int vA = (i < NPAD) ? degS[i] : 0;
    int vB = (i < NPAD) ? degD[i] : 0;
    if (i < NN) invd[i] = vB > 0 ? 1.f/(float)vB : 0.f;
    int sA = vA, sB = vB;
    #pragma unroll
    for (int off=1; off<64; off<<=1){
      int tA = __shfl_up(sA, off), tB = __shfl_up(sB, off);
      if (lane >= off){ sA += tA; sB += tB; }
    }
    if (lane == 63){ wsA[wv] = sA; wsB[wv] = sB; }
    __syncthreads();
    if (wv == 0 && lane < 16){
      int w = wsA[lane];
      #pragma unroll
      for (int off=1; off<16; off<<=1){ int t = __shfl_up(w, off); if (lane >= off) w += t; }
      wsA[lane] = w;
    }
    if (wv == 1 && lane < 16){
      int w = wsB[lane];
      #pragma unroll
      for (int off=1; off<16; off<<=1){ int t = __shfl_up(w, off); if (lane >= off) w += t; }
      wsB[lane] = w;
    }
    __syncthreads();
    int wbA = wv ? wsA[wv-1] : 0;
    int wbB = wv ? wsB[wv-1] : 0;
    if (i < NPAD){ rowptr[i+1] = baseA + wbA + sA; rowptrD[i+1] = baseB + wbB + sB; }
    __syncthreads();
    if (tid == 0){ baseA += wsA[15]; baseB += wsB[15]; }
    __syncthreads();
  }
  int s = (tid < 512) ? ghist[tid] : 0;
  #pragma unroll
  for (int off=1; off<64; off<<=1){ int t = __shfl_up(s, off); if (lane >= off) s += t; }
  if (tid < 512 && lane == 63) wsA[wv] = s;
  __syncthreads();
  if (wv == 0 && lane < 8){
    int w = wsA[lane];
    #pragma unroll
    for (int off=1; off<8; off<<=1){ int t = __shfl_up(w, off); if (lane >= off) w += t; }
    wsA[lane] = w;
  }
  __syncthreads();
  if (tid < 512){
    int wb = wv ? wsA[wv-1] : 0;
    gptr[tid+1] = wb + s;
    if (tid == 0) gptr[0] = 0;
  }
}

// scatter: src-sorted pos gets edge id + dst-sorted position
__global__ __launch_bounds__(256) void k_scatter(const int* __restrict__ src, const int* __restrict__ dst,
                         const int* __restrict__ rowptr, int* __restrict__ cnt,
                         const int* __restrict__ rowptrD, int* __restrict__ cntD,
                         int* __restrict__ sEid, int* __restrict__ sDpos){
  int e = blockIdx.x*blockDim.x + threadIdx.x;
  if (e >= NE) return;
  int s = src[e], d = dst[e];
  int pos = rowptr[s] + atomicAdd(&cnt[s], 1);
  sEid[pos] = e;
  sDpos[pos] = rowptrD[d] + atomicAdd(&cntD[d], 1);
}

// e1 sorted, wave-per-position; pad rows zeroed; ea row read is a wave-broadcast
__global__ __launch_bounds__(256) void k_e1s(const float* __restrict__ ea, const float* __restrict__ w,
                     const float* __restrict__ b, const int* __restrict__ sEid,
                     unsigned short* __restrict__ e1s){
  int pos = (blockIdx.x*blockDim.x + threadIdx.x) >> 6;
  int lane = threadIdx.x & 63;
  if (pos >= NE + 16) return;
  if (pos >= NE){ e1s[(size_t)pos*DD + lane] = 0; return; }
  int e = sEid[pos];
  const float* er = ea + (size_t)e*4;
  float a0 = er[0], a1 = er[1], a2 = er[2], a3 = er[3];
  const float* wr = w + lane*4;
  float acc = b[lane] + a0*wr[0] + a1*wr[1] + a2*wr[2] + a3*wr[3];
  e1s[(size_t)pos*DD + lane] = f2bf(lk(acc));
}

// ---------- fused message kernel (round-14 structure; bf16 msgbuf) ----------
__global__ __launch_bounds__(512) void k_fused8(const unsigned short* __restrict__ w2t,
                                                const unsigned short* __restrict__ hbf,
                                                const unsigned short* __restrict__ e1s,
                                                const int* __restrict__ sDpos,
                                                const int* __restrict__ rowptr,
                                                unsigned short* __restrict__ msgbuf){
  extern __shared__ char smem[];
  int lane = threadIdx.x & 63;
  int wv   = threadIdx.x >> 6;           // 0..7
  int xcd = blockIdx.x & 7, q = blockIdx.x >> 3;
  int g = xcd*781 + (xcd < 4 ? xcd : 4) + q;
  int n0 = (g >> 2) * 16;
  int oq = g & 3;
  int r16 = lane & 15, kg = lane >> 4;

  const unsigned short* hp = hbf + (size_t)(n0 + r16)*DD;
  bf8 bh0 = *(const bf8*)(hp + kg*8);
  bf8 bh1 = *(const bf8*)(hp + 32 + kg*8);

  // phase A
  {
    const unsigned short* wq = w2t + (size_t)oq*TPQ*1024;
    int nsw = r16 & 7;
    for (int tq = wv; tq < TPQ; tq += 8){
      const unsigned short* wp = wq + (size_t)tq*1024;
      bf8 a0 = *(const bf8*)(wp + lane*8);
      bf8 a1 = *(const bf8*)(wp + 512 + lane*8);
      f32x4 acc = {0.f,0.f,0.f,0.f};
      acc = __builtin_amdgcn_mfma_f32_16x16x32_bf16(a0, bh0, acc, 0,0,0);
      acc = __builtin_amdgcn_mfma_f32_16x16x32_bf16(a1, bh1, acc, 0,0,0);
      unsigned u0 = (unsigned)f2bf(acc[0]) | ((unsigned)f2bf(acc[1]) << 16);
      unsigned u1 = (unsigned)f2bf(acc[2]) | ((unsigned)f2bf(acc[3]) << 16);
      unsigned long long ull = (unsigned long long)u0 | ((unsigned long long)u1 << 32);
      if (tq < 64){
        int o_rel = tq >> 2;
        int s = ((tq & 3) << 1) + (kg >> 1);
        int slot = s ^ (o_rel & 7) ^ nsw;
        *(unsigned long long*)(smem + (size_t)r16*NSTRIDE + o_rel*128 + (slot<<4) + ((kg & 1)*8)) = ull;
      } else {
        *(unsigned long long*)(smem + (size_t)r16*NSTRIDE + 2048 + kg*8) = ull;
      }
    }
  }
  __syncthreads();

  // phase B (round-11 proven form; bf16 stores)
  #pragma unroll
  for (int s2 = 0; s2 < 2; ++s2){
    int nl = wv + 8*s2;
    int node = n0 + nl;
    int estart = rowptr[node], eend = rowptr[node + 1];
    const char* ab = smem + (size_t)nl*NSTRIDE;
    int nsw = nl & 7;
    int slot0 = (kg) ^ (r16 & 7) ^ nsw;
    int slot1 = (4 + kg) ^ (r16 & 7) ^ nsw;
    bf8 B0 = *(const bf8*)(ab + r16*128 + (slot0<<4));
    bf8 B1 = *(const bf8*)(ab + r16*128 + (slot1<<4));
    float bias = bf2f(*(const unsigned short*)(ab + 2048 + r16*2));
    for (int eg = estart; eg < eend; eg += 16){
      bf8 af0 = {0,0,0,0,0,0,0,0}, af1 = {0,0,0,0,0,0,0,0};
      int er = eg + r16;
      if (er < eend){
        af0 = *(const bf8*)(e1s + (size_t)er*DD + kg*8);
        af1 = *(const bf8*)(e1s + (size_t)er*DD + 32 + kg*8);
      }
      int ebase = eg + kg*4;
      int dp[4];
      #pragma unroll
      for (int j=0; j<4; ++j){
        int e = ebase + j;
        dp[j] = (e < eend) ? sDpos[e] : -1;
      }
      f32x4 acc = {0.f,0.f,0.f,0.f};
      acc = __builtin_amdgcn_mfma_f32_16x16x32_bf16(af0, B0, acc, 0,0,0);
      acc = __builtin_amdgcn_mfma_f32_16x16x32_bf16(af1, B1, acc, 0,0,0);
      #pragma unroll
      for (int j=0; j<4; ++j){
        if (dp[j] >= 0)
          msgbuf[(size_t)dp[j]*DD + oq*16 + r16] = f2bf(acc[j] + bias);
      }
    }
  }
}

// ---------- MFMA GRU: block = 16 nodes, 4 waves (bf16 msgbuf reads) ----------
__global__ __launch_bounds__(256) void k_gru(float* __restrict__ h, unsigned short* __restrict__ hbf,
                      const unsigned short* __restrict__ msgbuf, const int* __restrict__ rowptrD,
                      const float* __restrict__ invd,
                      const unsigned short* __restrict__ wgru,
                      const float* __restrict__ cb,
                      const float* __restrict__ bih, const float* __restrict__ bhh){
  __shared__ float msum[16*68];
  __shared__ unsigned short mbf[16*64];
  __shared__ float iv[16];
  int tid = threadIdx.x;
  int lane = tid & 63, wv = tid >> 6;
  int n0 = blockIdx.x * 16;
  int r16 = lane & 15, kg = lane >> 4;

  const unsigned short* hp = hbf + (size_t)(n0 + r16)*DD;
  bf8 af0 = *(const bf8*)(hp + kg*8);
  bf8 af1 = *(const bf8*)(hp + 32 + kg*8);

  if (tid < 16) iv[tid] = (n0 + tid < NN) ? invd[n0 + tid] : 0.f;
  #pragma unroll
  for (int q=0; q<4; ++q){
    int nl = wv*4 + q;
    int node = n0 + nl;
    float ms = 0.f;
    if (node < NN){
      int pa = rowptrD[node], pb = rowptrD[node+1];
      for (int p=pa; p<pb; ++p) ms += bf2f(msgbuf[(size_t)p*DD + lane]);
    }
    msum[nl*68 + lane] = ms;
  }
  __syncthreads();

  int o = wv*16 + r16;
  {
    const unsigned short* tp = wgru + (size_t)wv*1024;
    bf8 bc0 = *(const bf8*)(tp + lane*8);
    bf8 bc1 = *(const bf8*)(tp + 512 + lane*8);
    f32x4 cacc = {0.f,0.f,0.f,0.f};
    cacc = __builtin_amdgcn_mfma_f32_16x16x32_bf16(af0, bc0, cacc, 0,0,0);
    cacc = __builtin_amdgcn_mfma_f32_16x16x32_bf16(af1, bc1, cacc, 0,0,0);
    float cbo = cb[o];
    int gi_gran = o >> 3;
    #pragma unroll
    for (int j=0; j<4; ++j){
      int nl = kg*4 + j;
      float mval = lk(msum[nl*68 + o]*iv[nl] + cacc[j] + cbo);
      int swz = gi_gran ^ (nl & 7);
      *(unsigned short*)((char*)mbf + nl*128 + (swz<<4) + (o&7)*2) = f2bf(mval);
    }
  }
  __syncthreads();

  bf8 am0 = *(const bf8*)((char*)mbf + r16*128 + (((kg) ^ (r16 & 7))<<4));
  bf8 am1 = *(const bf8*)((char*)mbf + r16*128 + (((4 + kg) ^ (r16 & 7))<<4));

  f32x4 gi_r={0,0,0,0}, gi_z={0,0,0,0}, gi_n={0,0,0,0};
  f32x4 gh_r={0,0,0,0}, gh_z={0,0,0,0}, gh_n={0,0,0,0};
  {
    const unsigned short* t0 = wgru + (size_t)(4 + 0*4 + wv)*1024;
    const unsigned short* t1 = wgru + (size_t)(4 + 1*4 + wv)*1024;
    const unsigned short* t2 = wgru + (size_t)(4 + 2*4 + wv)*1024;
    const unsigned short* u0 = wgru + (size_t)(16 + 0*4 + wv)*1024;
    const unsigned short* u1 = wgru + (size_t)(16 + 1*4 + wv)*1024;
    const unsigned short* u2 = wgru + (size_t)(16 + 2*4 + wv)*1024;
    gi_r = __builtin_amdgcn_mfma_f32_16x16x32_bf16(am0, *(const bf8*)(t0 + lane*8), gi_r, 0,0,0);
    gi_r = __builtin_amdgcn_mfma_f32_16x16x32_bf16(am1, *(const bf8*)(t0 + 512 + lane*8), gi_r, 0,0,0);
    gi_z = __builtin_amdgcn_mfma_f32_16x16x32_bf16(am0, *(const bf8*)(t1 + lane*8), gi_z, 0,0,0);
    gi_z = __builtin_amdgcn_mfma_f32_16x16x32_bf16(am1, *(const bf8*)(t1 + 512 + lane*8), gi_z, 0,0,0);
    gi_n = __builtin_amdgcn_mfma_f32_16x16x32_bf16(am0, *(const bf8*)(t2 + lane*8), gi_n, 0,0,0);
    gi_n = __builtin_amdgcn_mfma_f32_16x16x32_bf16(am1, *(const bf8*)(t2 + 512 + lane*8), gi_n, 0,0,0);
    gh_r = __builtin_amdgcn_mfma_f32_16x16x32_bf16(af0, *(const bf8*)(u0 + lane*8), gh_r, 0,0,0);
    gh_r = __builtin_amdgcn_mfma_f32_16x16x32_bf16(af1, *(const bf8*)(u0 + 512 + lane*8), gh_r, 0,0,0);
    gh_z = __builtin_amdgcn_mfma_f32_16x16x32_bf16(af0, *(const bf8*)(u1 + lane*8), gh_z, 0,0,0);
    gh_z = __builtin_amdgcn_mfma_f32_16x16x32_bf16(af1, *(const bf8*)(u1 + 512 + lane*8), gh_z, 0,0,0);
    gh_n = __builtin_amdgcn_mfma_f32_16x16x32_bf16(af0, *(const bf8*)(u2 + lane*8), gh_n, 0,0,0);
    gh_n = __builtin_amdgcn_mfma_f32_16x16x32_bf16(af1, *(const bf8*)(u2 + 512 + lane*8), gh_n, 0,0,0);
  }
  float bi0 = bih[o], bi1 = bih[64+o], bi2 = bih[128+o];
  float bh0 = bhh[o], bh1 = bhh[64+o], bh2 = bhh[128+o];
  #pragma unroll
  for (int j=0; j<4; ++j){
    int node = n0 + kg*4 + j;
    if (node < NN){
      size_t idx = (size_t)node*DD + o;
      float hv = h[idx];
      float r = sg(gi_r[j] + bi0 + gh_r[j] + bh0);
      float z = sg(gi_z[j] + bi1 + gh_z[j] + bh1);
      float nn = tanhf(gi_n[j] + bi2 + r*(gh_n[j] + bh2));
      float nh = (1.f - z)*nn + z*hv;
      h[idx] = nh;
      hbf[idx] = f2bf(nh);
    }
  }
}

// ---------- heads ----------
__global__ __launch_bounds__(256) void k_jbond(const float* __restrict__ h, const int* __restrict__ idx,
                        const float* __restrict__ w1T, const float* __restrict__ b1,
                        const float* __restrict__ w2, const float* __restrict__ b2,
                        float* __restrict__ jtmp){
  int wid = (blockIdx.x*blockDim.x + threadIdx.x) >> 6;
  int lane = threadIdx.x & 63;
  if (wid >= NJ*2) return;
  int a = idx[wid];
  float f = h[(size_t)a*DD + lane];
  float acc = b1[lane];
  for (int i=0; i<DD; ++i) acc += __shfl(f, i) * w1T[i*DD + lane];
  float p = lk(acc) * w2[lane];
  #pragma unroll
  for (int off=32; off; off>>=1) p += __shfl_xor(p, off);
  if (lane == 0) jtmp[wid] = p + b2[0];
}
__global__ __launch_bounds__(256) void k_jmean(const float* __restrict__ jtmp, float* __restrict__ o){
  int j = blockIdx.x*blockDim.x + threadIdx.x;
  if (j < NJ) o[j] = 0.5f*(jtmp[2*j] + jtmp[2*j+1]);
}
__global__ __launch_bounds__(256) void k_stem1(const float* __restrict__ h, const int* __restrict__ idx,
                        const float* __restrict__ w1T, const float* __restrict__ b1,
                        float* __restrict__ st1){
  int wid = (blockIdx.x*blockDim.x + threadIdx.x) >> 6;
  int lane = threadIdx.x & 63;
  if (wid >= NS) return;
  int a = idx[wid];
  float f = h[(size_t)a*DD + lane];
  float acc = b1[lane];
  for (int i=0; i<DD; ++i) acc += __shfl(f, i) * w1T[i*DD + lane];
  st1[(size_t)wid*DD + lane] = lk(acc);
}
__global__ __launch_bounds__(256) void k_stem2(const float* __restrict__ st1, const float* __restrict__ w2T,
                        const float* __restrict__ b2, float* __restrict__ o){
  int i = blockIdx.x*blockDim.x + threadIdx.x;
  if (i >= NS*NO) return;
  int r = i / NO, c = i - r*NO;
  float acc = b2[c];
  const float* t1 = st1 + (size_t)r*DD;
  for (int k=0; k<DD; ++k) acc += t1[k]*w2T[k*NO + c];
  o[i] = acc;
}

// ---------- Set2Set ----------
__global__ void k_qvec(const float* __restrict__ bih, const float* __restrict__ bhh, float* __restrict__ qv){
  int g = threadIdx.x;
  float gi = bih[g] + bhh[g];
  float gg = bih[128+g] + bhh[128+g];
  float go = bih[192+g] + bhh[192+g];
  float c = sg(gi)*tanhf(gg);
  qv[g] = sg(go)*tanhf(c);
}
__global__ __launch_bounds__(256) void k_e(const float* __restrict__ h, const float* __restrict__ qv,
                    const int* __restrict__ batch, float* __restrict__ evec, unsigned* __restrict__ emax){
  int n = (blockIdx.x*blockDim.x + threadIdx.x) >> 6;
  int lane = threadIdx.x & 63;
  if (n >= NN) return;
  float p = h[(size_t)n*DD + lane] * qv[lane];
  #pragma unroll
  for (int off=32; off; off>>=1) p += __shfl_xor(p, off);
  if (lane == 0){
    evec[n] = p;
    atomicMax(&emax[batch[n]], fenc(p));
  }
}
// block per graph, 4 waves stride the node list (serial depth /4), LDS combine
__global__ __launch_bounds__(256) void k_gsum(const float* __restrict__ h, const float* __restrict__ evec,
                       const unsigned* __restrict__ emax, const int* __restrict__ gptr,
                       float* __restrict__ rvec){
  __shared__ float part[4][64];
  __shared__ float ps[4];
  int g = blockIdx.x;
  int lane = threadIdx.x & 63, wv = threadIdx.x >> 6;
  int a = gptr[g], b = gptr[g+1];
  float m = fdec(emax[g]);
  float s = 0.f, vacc = 0.f;
  for (int n = a + wv; n < b; n += 4){
    float ex = expf(evec[n] - m);
    s += ex;
    vacc += ex * h[(size_t)n*DD + lane];
  }
  part[wv][lane] = vacc;
  if (lane == 0) ps[wv] = s;
  __syncthreads();
  if (wv == 0){
    float v = part[0][lane] + part[1][lane] + part[2][lane] + part[3][lane];
    float st = ps[0] + ps[1] + ps[2] + ps[3];
    rvec[(size_t)g*DD + lane] = (b > a) ? v/st : 0.f;
  }
}
__global__ __launch_bounds__(256) void k_gout(const float* __restrict__ qv, const float* __restrict__ rvec,
                       const float* __restrict__ lw, const float* __restrict__ lb, float* __restrict__ o){
  int t = blockIdx.x*blockDim.x + threadIdx.x;
  if (t >= NGG*2) return;
  int g = t >> 1, c = t & 1;
  float acc = lb[c];
  for (int j=0; j<DD; ++j) acc += qv[j]*lw[c*128 + j];
  for (int j=0; j<DD; ++j) acc += rvec[(size_t)g*DD + j]*lw[c*128 + 64 + j];
  o[g*2 + c] = acc;
}

// ---------- host ----------
extern "C" void kernel_launch(void* const* d_in, const int* in_sizes, int n_in,
                              void* d_out_, int out_size, void* d_ws, size_t ws_size,
                              hipStream_t stream){
  const float* x        = (const float*)d_in[0];
  const int*   ei       = (const int*)d_in[1];
  const float* eattr    = (const float*)d_in[2];
  const int*   jbidx    = (const int*)d_in[3];
  const int*   stidx    = (const int*)d_in[4];
  const int*   batch    = (const int*)d_in[5];
  const float* lin0_w   = (const float*)d_in[6];
  const float* lin0_b   = (const float*)d_in[7];
  const float* net1_w   = (const float*)d_in[8];
  const float* net1_b   = (const float*)d_in[9];
  const float* net2_w   = (const float*)d_in[10];
  const float* net2_b   = (const float*)d_in[11];
  const float* conv_root= (const float*)d_in[12];
  const float* conv_b   = (const float*)d_in[13];
  const float* gru_wih  = (const float*)d_in[14];
  const float* gru_whh  = (const float*)d_in[15];
  const float* gru_bih  = (const float*)d_in[16];
  const float* gru_bhh  = (const float*)d_in[17];
  const float* n2s_w1   = (const float*)d_in[18];
  const float* n2s_b1   = (const float*)d_in[19];
  const float* n2s_w2   = (const float*)d_in[20];
  const float* n2s_b2   = (const float*)d_in[21];
  const float* n2j_w1   = (const float*)d_in[22];
  const float* n2j_b1   = (const float*)d_in[23];
  const float* n2j_w2   = (const float*)d_in[24];
  const float* n2j_b2   = (const float*)d_in[25];
  const float* lstm_bih = (const float*)d_in[28];
  const float* lstm_bhh = (const float*)d_in[29];
  const float* lout_w   = (const float*)d_in[30];
  const float* lout_b   = (const float*)d_in[31];
  float* out = (float*)d_out_;

  const int* src = ei;
  const int* dst = ei + NE;

  char* ws = (char*)d_ws;
  size_t off = 0;
  auto alloc = [&](size_t bytes)->void*{
    void* p = ws + off; off = (off + bytes + 255) & ~(size_t)255; return p;
  };
  float* h    = (float*)alloc((size_t)NN*DD*4);
  unsigned short* msgbuf = (unsigned short*)alloc((size_t)(NE+1)*DD*2);   // bf16
  unsigned short* hbf = (unsigned short*)alloc((size_t)NPAD*DD*2);
  unsigned short* e1s = (unsigned short*)alloc((size_t)(NE+16)*DD*2);
  unsigned short* w2t = (unsigned short*)alloc((size_t)W2T_ELEMS*2);
  unsigned short* wgru = (unsigned short*)alloc((size_t)WG_ELEMS*2);
  // ---- zeroed group (one memset) ----
  int* degS   = (int*)alloc((size_t)NPAD*4);
  int* cnt    = (int*)alloc((size_t)NPAD*4);
  int* degD   = (int*)alloc((size_t)NPAD*4);
  int* cntD   = (int*)alloc((size_t)NPAD*4);
  int* ghist  = (int*)alloc((size_t)NGG*4);
  unsigned* emax = (unsigned*)alloc((size_t)NGG*4);
  char* zend = ws + off;
  // ---- rest ----
  int* rowptr  = (int*)alloc((size_t)(NPAD+1)*4);
  int* rowptrD = (int*)alloc((size_t)(NPAD+1)*4);
  int* gptr    = (int*)alloc((size_t)(NGG+1)*4);
  int* sEid   = (int*)alloc((size_t)NE*4);
  int* sDpos  = (int*)alloc((size_t)NE*4);
  float* invd = (float*)alloc((size_t)NN*4);
  float* w1jT = (float*)alloc((size_t)DD*DD*4);
  float* w1sT = (float*)alloc((size_t)DD*DD*4);
  float* w2sT = (float*)alloc((size_t)DD*NO*4);
  float* evec = (float*)alloc((size_t)NN*4);
  float* rvec  = (float*)alloc((size_t)NGG*DD*4);
  float* qv    = (float*)alloc((size_t)DD*4);
  float* jtmp  = (float*)alloc((size_t)NJ*2*4);
  float* st1   = (float*)alloc((size_t)NS*DD*4);

  hipFuncSetAttribute((const void*)k_fused8, hipFuncAttributeMaxDynamicSharedMemorySize, LDSB);

  // ---- setup (5 kernels + 1 memset) ----
  hipMemsetAsync(degS, 0, (size_t)(zend - (char*)degS), stream);
  k_setup<<<SB6, 256, 0, stream>>>(x, lin0_w, lin0_b, h, hbf,
                                   net2_w, net2_b, w2t,
                                   conv_root, gru_wih, gru_whh, wgru,
                                   n2j_w1, w1jT, n2s_w1, w1sT, n2s_w2, w2sT);
  k_hist2<<<489, 256, 0, stream>>>(src, dst, degS, degD, batch, ghist);
  k_scan2<<<1, 1024, 0, stream>>>(degS, degD, rowptr, rowptrD, invd, ghist, gptr);
  k_scatter<<<391, 256, 0, stream>>>(src, dst, rowptr, cnt, rowptrD, cntD, sEid, sDpos);
  k_e1s<<<25004, 256, 0, stream>>>(eattr, net1_w, net1_b, sEid, e1s);

  // ---- 6 message-passing + GRU iterations ----
  for (int it=0; it<6; ++it){
    k_fused8<<<TOTBLK, 512, LDSB, stream>>>(w2t, hbf, e1s, sDpos, rowptr, msgbuf);
    k_gru<<<NBLK, 256, 0, stream>>>(h, hbf, msgbuf, rowptrD, invd, wgru, conv_b, gru_bih, gru_bhh);
  }

  // ---- heads ----
  k_jbond<<<512, 256, 0, stream>>>(h, jbidx, w1jT, n2j_b1, n2j_w2, n2j_b2, jtmp);
  k_jmean<<<4, 256, 0, stream>>>(jtmp, out + NGG*2 + NS*NO);
  k_stem1<<<512, 256, 0, stream>>>(h, stidx, w1sT, n2s_b1, st1);
  k_stem2<<<840, 256, 0, stream>>>(st1, w2sT, n2s_b2, out + NGG*2);

  // ---- Set2Set ----
  k_qvec<<<1, 64, 0, stream>>>(lstm_bih, lstm_bhh, qv);
  k_e<<<6250, 256, 0, stream>>>(h, qv, batch, evec, emax);
  k_gsum<<<NGG, 256, 0, stream>>>(h, evec, emax, gptr, rvec);
  k_gout<<<4, 256, 0, stream>>>(qv, rvec, lout_w, lout_b, out);
}